// Round 2
// baseline (7478.790 us; speedup 1.0000x reference)
//
#include <hip/hip_runtime.h>

typedef unsigned short u16;
typedef unsigned int u32;

#define NPTS 131072
#define CD 128
#define KOFF 27
#define MMAP 65536
#define TOTE (KOFF * MMAP)  // 1769472 entries
#define LDAB 136            // LDS row stride in u16 (128+8 pad)

__device__ __forceinline__ u16 f2bf(float f) {  // f32 -> bf16 RNE
  u32 u = __float_as_uint(f);
  u32 r = (u + 0x7fffu + ((u >> 16) & 1u)) >> 16;
  return (u16)r;
}

typedef __attribute__((ext_vector_type(8))) short bf16x8;
typedef __attribute__((ext_vector_type(4))) float f32x4;

// ---------------- dtype conversion ----------------
__global__ __launch_bounds__(256) void k_convert_x(const float* __restrict__ x,
                                                   u16* __restrict__ xb) {
  long i = ((long)blockIdx.x * 256 + threadIdx.x) * 8;
  float4 a = *(const float4*)(x + i);
  float4 b = *(const float4*)(x + i + 4);
  uint4 v;
  v.x = f2bf(a.x) | ((u32)f2bf(a.y) << 16);
  v.y = f2bf(a.z) | ((u32)f2bf(a.w) << 16);
  v.z = f2bf(b.x) | ((u32)f2bf(b.y) << 16);
  v.w = f2bf(b.z) | ((u32)f2bf(b.w) << 16);
  *(uint4*)(xb + i) = v;
}

// W [K][ci][co] f32 -> Wb [K][co][ci] bf16
__global__ __launch_bounds__(256) void k_convert_w(const float* __restrict__ W,
                                                   u16* __restrict__ Wb) {
  int idx = blockIdx.x * 256 + threadIdx.x;
  if (idx >= KOFF * 2048) return;
  int k = idx >> 11;
  int rem = idx & 2047;
  int co = rem >> 4;
  int cc = rem & 15;
  const float* ws = W + (long)k * (CD * CD) + (long)(cc * 8) * CD + co;
  u16 t[8];
#pragma unroll
  for (int j = 0; j < 8; ++j) t[j] = f2bf(ws[j * CD]);
  uint4 v;
  v.x = t[0] | ((u32)t[1] << 16);
  v.y = t[2] | ((u32)t[3] << 16);
  v.z = t[4] | ((u32)t[5] << 16);
  v.w = t[6] | ((u32)t[7] << 16);
  ((uint4*)Wb)[idx] = v;
}

// ---------------- sort 1: counting sort of all entries by output row ----------------
__global__ __launch_bounds__(256) void k_hist(const int* __restrict__ mo,
                                              u32* __restrict__ hist) {
  int i = blockIdx.x * 256 + threadIdx.x;  // grid exact TOTE
  atomicAdd(&hist[mo[i]], 1u);
}

__global__ __launch_bounds__(256) void k_scanA(const u32* __restrict__ hist,
                                               u32* __restrict__ offs,
                                               u32* __restrict__ bsum) {
  __shared__ u32 sh[256];
  int t = threadIdx.x, b = blockIdx.x, i = b * 256 + t;
  u32 v = hist[i];
  u32 run = v;
  sh[t] = run;
  __syncthreads();
  for (int d = 1; d < 256; d <<= 1) {
    u32 y = (t >= d) ? sh[t - d] : 0u;
    __syncthreads();
    run += y;
    sh[t] = run;
    __syncthreads();
  }
  offs[i] = run - v;  // exclusive within block
  if (t == 255) bsum[b] = run;
}

__global__ __launch_bounds__(512) void k_scanB(u32* __restrict__ bsum) {
  __shared__ u32 sh[512];
  int t = threadIdx.x;
  u32 v = bsum[t];
  u32 run = v;
  sh[t] = run;
  __syncthreads();
  for (int d = 1; d < 512; d <<= 1) {
    u32 y = (t >= d) ? sh[t - d] : 0u;
    __syncthreads();
    run += y;
    sh[t] = run;
    __syncthreads();
  }
  bsum[t] = run - v;  // exclusive
}

__global__ __launch_bounds__(256) void k_scanC(u32* __restrict__ offs,
                                               const u32* __restrict__ bsum) {
  int t = threadIdx.x, b = blockIdx.x, i = b * 256 + t;
  offs[i] += bsum[b];
  if (i == 0) offs[NPTS] = TOTE;
}

__global__ __launch_bounds__(256) void k_place(const int* __restrict__ mo,
                                               const u32* __restrict__ offs,
                                               u32* __restrict__ cur,
                                               u32* __restrict__ perm) {
  int i = blockIdx.x * 256 + threadIdx.x;
  int o = mo[i];
  u32 p = offs[o] + atomicAdd(&cur[o], 1u);
  perm[p] = (u32)i;  // global entry id e = k*MMAP+m
}

// ---------------- sort 2: group ranks by (output_chunk, k) ----------------
__global__ __launch_bounds__(256) void k_hist2(const int* __restrict__ mo,
                                               u32* __restrict__ hist2,
                                               int shift, int binsTot) {
  extern __shared__ u32 lh[];
  int t = threadIdx.x;
  for (int i = t; i < binsTot; i += 256) lh[i] = 0;
  __syncthreads();
  int base = blockIdx.x * 4096 + t;
#pragma unroll
  for (int j = 0; j < 16; ++j) {
    int e = base + j * 256;
    int row = mo[e];
    int bin = (row >> shift) * KOFF + (e >> 16);
    atomicAdd(&lh[bin], 1u);
  }
  __syncthreads();
  for (int i = t; i < binsTot; i += 256)
    if (lh[i]) atomicAdd(&hist2[i], lh[i]);
}

// offs2 (global exclusive scan over bins) + per-chunk block-count prefix `pre`
__global__ __launch_bounds__(64) void k_scan2(const u32* __restrict__ hist2,
                                              u32* __restrict__ offs2,
                                              u32* __restrict__ pre, int chunks) {
  __shared__ u32 csum[65];
  int t = threadIdx.x;
  if (t < chunks) {
    u32 s = 0;
    for (int k = 0; k < KOFF; ++k) s += hist2[t * KOFF + k];
    csum[t] = s;
  }
  __syncthreads();
  if (t == 0) {
    u32 r = 0;
    for (int c = 0; c < chunks; ++c) {
      u32 v = csum[c];
      csum[c] = r;
      r += v;
    }
  }
  __syncthreads();
  if (t < chunks) {
    u32 r = csum[t];
    u32 bp = 0;
    for (int k = 0; k < KOFF; ++k) {
      u32 cnt = hist2[t * KOFF + k];
      offs2[t * KOFF + k] = r;
      r += cnt;
      pre[t * 28 + k] = bp;
      bp += (cnt + 63) >> 6;
    }
    pre[t * 28 + KOFF] = bp;
  }
  if (t == 0) offs2[chunks * KOFF] = TOTE;
}

__global__ __launch_bounds__(256) void k_place2(const int* __restrict__ mo,
                                                const u32* __restrict__ perm,
                                                const u32* __restrict__ offs2,
                                                u32* __restrict__ cur2,
                                                u32* __restrict__ perm2p, int shift) {
  int p = blockIdx.x * 256 + threadIdx.x;
  u32 e = perm[p];
  int row = mo[e];
  int bin = (row >> shift) * KOFF + (int)(e >> 16);
  u32 pos = offs2[bin] + atomicAdd(&cur2[bin], 1u);
  perm2p[pos] = (u32)p;
}

// ---------------- gather-GEMM with rank-scatter stores ----------------
__global__ __launch_bounds__(256) void k_gemm2(const u16* __restrict__ src,
                                               const u16* __restrict__ Wb,
                                               const int* __restrict__ mi,
                                               const u32* __restrict__ perm,
                                               const u32* __restrict__ perm2p,
                                               const u32* __restrict__ offs,
                                               const u32* __restrict__ offs2,
                                               const u32* __restrict__ pre,
                                               u16* __restrict__ contrib,
                                               int c, int R, u32 capRows) {
  __shared__ u16 As[64 * LDAB];
  __shared__ u16 Bs[128 * LDAB];
  __shared__ u32 sin[64];
  __shared__ u32 srow[64];
  const int t = threadIdx.x;
  const u32 b = blockIdx.x;
  const u32* cpre = pre + c * 28;
  if (b >= cpre[KOFF]) return;
  int k = 0;
  while (cpre[k + 1] <= b) ++k;
  const u32 bin = (u32)c * KOFF + k;
  const u32 P = offs2[bin] + (b - cpre[k]) * 64u;
  const u32 binEnd = offs2[bin + 1];
  const int nv = (int)((binEnd - P < 64u) ? (binEnd - P) : 64u);
  const u32 chunkStart = offs[(u32)c * (u32)R];

  if (t < 64) {
    u32 inr = 0, sr = 0xffffffffu;
    if (t < nv) {
      u32 p = perm2p[P + t];
      u32 e = perm[p];
      inr = (u32)mi[e];
      sr = p - chunkStart;
    }
    sin[t] = inr;
    srow[t] = sr;
  }
  const uint4* wsrc = (const uint4*)(Wb + (long)k * (CD * CD));
#pragma unroll
  for (int i = 0; i < 8; ++i) {
    int q = i * 256 + t;
    int co = q >> 4, cc = q & 15;
    *(uint4*)&Bs[co * LDAB + cc * 8] = wsrc[q];
  }
  __syncthreads();
#pragma unroll
  for (int i = 0; i < 4; ++i) {
    int q = i * 256 + t;
    int r = q >> 4, cc = q & 15;
    long row = sin[r];
    *(uint4*)&As[r * LDAB + cc * 8] = ((const uint4*)(src + row * CD))[cc];
  }
  __syncthreads();

  const int wave = t >> 6, lane = t & 63;
  const int lr = lane & 15, quad = lane >> 4;
  const int wm = (wave & 1) * 32;
  const int wn = (wave >> 1) * 64;
  f32x4 acc[2][4] = {};
#pragma unroll
  for (int kk = 0; kk < 4; ++kk) {
    bf16x8 a[2], bfr[4];
#pragma unroll
    for (int mt = 0; mt < 2; ++mt)
      a[mt] = *(const bf16x8*)&As[(wm + mt * 16 + lr) * LDAB + (kk * 4 + quad) * 8];
#pragma unroll
    for (int nt = 0; nt < 4; ++nt)
      bfr[nt] = *(const bf16x8*)&Bs[(wn + nt * 16 + lr) * LDAB + (kk * 4 + quad) * 8];
#pragma unroll
    for (int mt = 0; mt < 2; ++mt)
#pragma unroll
      for (int nt = 0; nt < 4; ++nt)
        acc[mt][nt] = __builtin_amdgcn_mfma_f32_16x16x32_bf16(a[mt], bfr[nt], acc[mt][nt], 0, 0, 0);
  }

  // C/D layout: col = lane&15, row = quad*4+reg
#pragma unroll
  for (int mt = 0; mt < 2; ++mt) {
#pragma unroll
    for (int v = 0; v < 4; ++v) {
      int slot = wm + mt * 16 + quad * 4 + v;
      u32 sr = srow[slot];
      if (sr < capRows) {
        u16* orow = contrib + (long)sr * CD;
#pragma unroll
        for (int nt = 0; nt < 4; ++nt) orow[wn + nt * 16 + lr] = f2bf(acc[mt][nt][v]);
      }
    }
  }
}

// ---------------- sequential segmented reduce + fused BN stats ----------------
__global__ __launch_bounds__(256) void k_segreduce2(const u16* __restrict__ contrib,
                                                    const u32* __restrict__ offs,
                                                    float* __restrict__ acc,
                                                    float* __restrict__ stats,
                                                    int c, int R) {
  const int wave = threadIdx.x >> 6, lane = threadIdx.x & 63;
  const int w = blockIdx.x * 4 + wave;  // 1024 waves
  const u32 chunkStart = offs[(u32)c * (u32)R];
  float sx = 0.f, sx2 = 0.f, sy = 0.f, sy2 = 0.f;
  const int rbase = c * R;
  for (int row = rbase + w; row < rbase + R; row += 1024) {
    u32 s0 = offs[row] - chunkStart, s1 = offs[row + 1] - chunkStart;
    float a0 = 0.f, b0 = 0.f, a1 = 0.f, b1 = 0.f;
    u32 e = s0;
    for (; e + 2 <= s1; e += 2) {
      u32 d0 = ((const u32*)(contrib + (long)e * CD))[lane];
      u32 d1 = ((const u32*)(contrib + (long)(e + 1) * CD))[lane];
      a0 += __uint_as_float(d0 << 16);
      b0 += __uint_as_float(d0 & 0xffff0000u);
      a1 += __uint_as_float(d1 << 16);
      b1 += __uint_as_float(d1 & 0xffff0000u);
    }
    if (e < s1) {
      u32 d0 = ((const u32*)(contrib + (long)e * CD))[lane];
      a0 += __uint_as_float(d0 << 16);
      b0 += __uint_as_float(d0 & 0xffff0000u);
    }
    float cx = a0 + a1, cy = b0 + b1;
    ((float2*)(acc + (long)row * CD))[lane] = make_float2(cx, cy);
    sx += cx;
    sx2 += cx * cx;
    sy += cy;
    sy2 += cy * cy;
  }
  __shared__ float sh[1024];
  sh[threadIdx.x] = sx;
  sh[256 + threadIdx.x] = sx2;
  sh[512 + threadIdx.x] = sy;
  sh[768 + threadIdx.x] = sy2;
  __syncthreads();
  if (threadIdx.x < 64) {
    int l = threadIdx.x;
    float vx = sh[l] + sh[l + 64] + sh[l + 128] + sh[l + 192];
    float vx2 = sh[256 + l] + sh[256 + l + 64] + sh[256 + l + 128] + sh[256 + l + 192];
    float vy = sh[512 + l] + sh[512 + l + 64] + sh[512 + l + 128] + sh[512 + l + 192];
    float vy2 = sh[768 + l] + sh[768 + l + 64] + sh[768 + l + 128] + sh[768 + l + 192];
    atomicAdd(&stats[2 * l], vx);
    atomicAdd(&stats[128 + 2 * l], vx2);
    atomicAdd(&stats[2 * l + 1], vy);
    atomicAdd(&stats[128 + 2 * l + 1], vy2);
  }
}

// ---------------- BN finalize / apply ----------------
__global__ void k_finalize(const float* __restrict__ stats, const float* __restrict__ gamma,
                           const float* __restrict__ beta, float* __restrict__ scsh) {
  int c = threadIdx.x;
  float mean = stats[c] * (1.f / NPTS);
  float var = stats[128 + c] * (1.f / NPTS) - mean * mean;
  float sc = rsqrtf(var + 1e-5f) * gamma[c];
  scsh[c] = sc;
  scsh[128 + c] = beta[c] - mean * sc;
}

__device__ __forceinline__ float elu(float v) { return v > 0.f ? v : expf(v) - 1.f; }

__global__ __launch_bounds__(256) void k_apply_mid(const float* __restrict__ acc,
                                                   const float* __restrict__ scsh,
                                                   u16* __restrict__ y) {
  long i = ((long)blockIdx.x * 256 + threadIdx.x) * 4;
  int c = (int)(i & 127);
  float4 a = *(const float4*)(acc + i);
  float r0 = elu(a.x * scsh[c] + scsh[128 + c]);
  float r1 = elu(a.y * scsh[c + 1] + scsh[129 + c]);
  float r2 = elu(a.z * scsh[c + 2] + scsh[130 + c]);
  float r3 = elu(a.w * scsh[c + 3] + scsh[131 + c]);
  uint2 v;
  v.x = f2bf(r0) | ((u32)f2bf(r1) << 16);
  v.y = f2bf(r2) | ((u32)f2bf(r3) << 16);
  *(uint2*)(y + i) = v;
}

__global__ __launch_bounds__(256) void k_apply_final(const float* __restrict__ acc,
                                                     const float* __restrict__ scsh,
                                                     const float* __restrict__ x,
                                                     float* __restrict__ out) {
  long i = ((long)blockIdx.x * 256 + threadIdx.x) * 4;
  int c = (int)(i & 127);
  float4 a = *(const float4*)(acc + i);
  float4 rx = *(const float4*)(x + i);
  float4 o;
  o.x = elu(a.x * scsh[c] + scsh[128 + c] + rx.x);
  o.y = elu(a.y * scsh[c + 1] + scsh[129 + c] + rx.y);
  o.z = elu(a.z * scsh[c + 2] + scsh[130 + c] + rx.z);
  o.w = elu(a.w * scsh[c + 3] + scsh[131 + c] + rx.w);
  *(float4*)(out + i) = o;
}

// ---------------- host ----------------
extern "C" void kernel_launch(void* const* d_in, const int* in_sizes, int n_in,
                              void* d_out, int out_size, void* d_ws, size_t ws_size,
                              hipStream_t stream) {
  const float* x = (const float*)d_in[0];
  const float* W1 = (const float*)d_in[1];
  const float* g1 = (const float*)d_in[2];
  const float* b1 = (const float*)d_in[3];
  const float* W2 = (const float*)d_in[4];
  const float* g2 = (const float*)d_in[5];
  const float* b2 = (const float*)d_in[6];
  const int* m1i = (const int*)d_in[7];
  const int* m1o = (const int*)d_in[8];
  const int* m2i = (const int*)d_in[9];
  const int* m2o = (const int*)d_in[10];
  float* out = (float*)d_out;

  // choose chunk count (output-row ranges) so contrib fits in ws
  size_t fixedBytes = 0;
  auto pad = [](size_t b) { return (b + 255) & ~(size_t)255; };
  // xb, yb, Wb1, Wb2, acc, hist, cur, hist2, cur2, stats, offs, offs2, pre, scsh, bsum, perm, perm2p
  int chunks = 1, shift = 17;
  u32 capRows = TOTE;
  for (int tryc = 1; tryc <= 64; tryc <<= 1) {
    int binsT = tryc * KOFF;
    size_t fb = pad((size_t)NPTS * CD * 2) * 2 + pad((size_t)KOFF * CD * CD * 2) * 2 +
                pad((size_t)NPTS * CD * 4) + pad((size_t)NPTS * 4) * 2 +
                pad((size_t)binsT * 4) * 2 + pad(256 * 4) + pad(((size_t)NPTS + 1) * 4) +
                pad(((size_t)binsT + 1) * 4) + pad((size_t)tryc * 28 * 4) + pad(256 * 4) +
                pad(512 * 4) + pad((size_t)TOTE * 4) * 2;
    u32 cap = (tryc == 1) ? (u32)TOTE : (u32)(TOTE / tryc + TOTE / tryc / 16 + 4096);
    cap = (cap + 63u) & ~63u;
    if (fb + (size_t)cap * 256 <= ws_size || tryc == 64) {
      chunks = tryc;
      capRows = cap;
      fixedBytes = fb;
      int lg = 0;
      while ((1 << lg) < tryc) ++lg;
      shift = 17 - lg;
      if (fb + (size_t)cap * 256 <= ws_size) break;
    }
  }
  (void)fixedBytes;
  const int R = NPTS / chunks;
  const int binsTot = chunks * KOFF;

  char* base = (char*)d_ws;
  size_t off = 0;
  auto alloc = [&](size_t bytes) -> void* {
    void* r = base + off;
    off = (off + bytes + 255) & ~(size_t)255;
    return r;
  };
  u16* xb = (u16*)alloc((size_t)NPTS * CD * 2);
  u16* yb = (u16*)alloc((size_t)NPTS * CD * 2);
  u16* Wb1 = (u16*)alloc((size_t)KOFF * CD * CD * 2);
  u16* Wb2 = (u16*)alloc((size_t)KOFF * CD * CD * 2);
  float* acc = (float*)alloc((size_t)NPTS * CD * 4);
  // ---- contiguous memset region: hist, cur, hist2, cur2, stats ----
  u32* hist = (u32*)alloc((size_t)NPTS * 4);
  u32* cur = (u32*)alloc((size_t)NPTS * 4);
  u32* hist2 = (u32*)alloc((size_t)binsTot * 4);
  u32* cur2 = (u32*)alloc((size_t)binsTot * 4);
  float* stats = (float*)alloc(256 * 4);
  size_t msSize = (size_t)((char*)base + off - (char*)hist);
  // ---- rest ----
  u32* offs = (u32*)alloc(((size_t)NPTS + 1) * 4);
  u32* offs2 = (u32*)alloc(((size_t)binsTot + 1) * 4);
  u32* pre = (u32*)alloc((size_t)chunks * 28 * 4);
  float* scsh = (float*)alloc(256 * 4);
  u32* bsum = (u32*)alloc(512 * 4);
  u32* perm = (u32*)alloc((size_t)TOTE * 4);
  u32* perm2p = (u32*)alloc((size_t)TOTE * 4);
  u16* contrib = (u16*)alloc((size_t)capRows * CD * 2);

  k_convert_x<<<(NPTS * CD) / 2048, 256, 0, stream>>>(x, xb);
  k_convert_w<<<(KOFF * 2048 + 255) / 256, 256, 0, stream>>>(W1, Wb1);
  k_convert_w<<<(KOFF * 2048 + 255) / 256, 256, 0, stream>>>(W2, Wb2);

  const int EB = TOTE / 256;       // 6912 blocks over entries
  const u32 maxB = capRows / 64 + KOFF;

  auto run_conv = [&](const u16* srcm, const u16* Wbm, const int* mi, const int* mo) {
    hipMemsetAsync(hist, 0, msSize, stream);
    k_hist<<<EB, 256, 0, stream>>>(mo, hist);
    k_scanA<<<512, 256, 0, stream>>>(hist, offs, bsum);
    k_scanB<<<1, 512, 0, stream>>>(bsum);
    k_scanC<<<512, 256, 0, stream>>>(offs, bsum);
    k_place<<<EB, 256, 0, stream>>>(mo, offs, cur, perm);
    k_hist2<<<432, 256, binsTot * 4, stream>>>(mo, hist2, shift, binsTot);
    k_scan2<<<1, 64, 0, stream>>>(hist2, offs2, pre, chunks);
    k_place2<<<EB, 256, 0, stream>>>(mo, perm, offs2, cur2, perm2p, shift);
    for (int c = 0; c < chunks; ++c) {
      k_gemm2<<<maxB, 256, 0, stream>>>(srcm, Wbm, mi, perm, perm2p, offs, offs2, pre,
                                        contrib, c, R, capRows);
      k_segreduce2<<<256, 256, 0, stream>>>(contrib, offs, acc, stats, c, R);
    }
  };

  run_conv(xb, Wb1, m1i, m1o);
  k_finalize<<<1, 128, 0, stream>>>(stats, g1, b1, scsh);
  k_apply_mid<<<(NPTS * CD) / 1024, 256, 0, stream>>>(acc, scsh, yb);

  run_conv(yb, Wb2, m2i, m2o);
  k_finalize<<<1, 128, 0, stream>>>(stats, g2, b2, scsh);
  k_apply_final<<<(NPTS * CD) / 1024, 256, 0, stream>>>(acc, scsh, x, out);
}

// Round 3
// 1450.834 us; speedup vs baseline: 5.1548x; 5.1548x over previous
//
#include <hip/hip_runtime.h>

typedef unsigned short u16;
typedef unsigned int u32;

#define NPTS 131072
#define CD 128
#define KOFF 27
#define MMAP 65536
#define LDAB 136   // LDS row stride (u16) for A/B tiles: 128+8
#define LDC 132    // LDS row stride (u16) for C repack: keeps store banks <=2-way

__device__ __forceinline__ u16 f2bf(float f) {  // f32 -> bf16 RNE
  u32 u = __float_as_uint(f);
  u32 r = (u + 0x7fffu + ((u >> 16) & 1u)) >> 16;
  return (u16)r;
}

typedef __attribute__((ext_vector_type(8))) short bf16x8;
typedef __attribute__((ext_vector_type(4))) float f32x4;

// ---------------- dtype conversion ----------------
__global__ __launch_bounds__(256) void k_convert_x(const float* __restrict__ x,
                                                   u16* __restrict__ xb) {
  long i = ((long)blockIdx.x * 256 + threadIdx.x) * 8;
  float4 a = *(const float4*)(x + i);
  float4 b = *(const float4*)(x + i + 4);
  uint4 v;
  v.x = f2bf(a.x) | ((u32)f2bf(a.y) << 16);
  v.y = f2bf(a.z) | ((u32)f2bf(a.w) << 16);
  v.z = f2bf(b.x) | ((u32)f2bf(b.y) << 16);
  v.w = f2bf(b.z) | ((u32)f2bf(b.w) << 16);
  *(uint4*)(xb + i) = v;
}

// W [K][ci][co] f32 -> Wb [K][co][ci] bf16
__global__ __launch_bounds__(256) void k_convert_w(const float* __restrict__ W,
                                                   u16* __restrict__ Wb) {
  int idx = blockIdx.x * 256 + threadIdx.x;
  if (idx >= KOFF * 2048) return;
  int k = idx >> 11;
  int rem = idx & 2047;
  int co = rem >> 4;
  int cc = rem & 15;
  const float* ws = W + (long)k * (CD * CD) + (long)(cc * 8) * CD + co;
  u16 t[8];
#pragma unroll
  for (int j = 0; j < 8; ++j) t[j] = f2bf(ws[j * CD]);
  uint4 v;
  v.x = t[0] | ((u32)t[1] << 16);
  v.y = t[2] | ((u32)t[3] << 16);
  v.z = t[4] | ((u32)t[5] << 16);
  v.w = t[6] | ((u32)t[7] << 16);
  ((uint4*)Wb)[idx] = v;
}

// ---------------- counting sort (per k-group) by output row ----------------
__global__ __launch_bounds__(256) void k_hist(const int* __restrict__ mo,
                                              u32* __restrict__ hist) {
  int i = blockIdx.x * 256 + threadIdx.x;  // grid exact cnt/256
  atomicAdd(&hist[mo[i]], 1u);
}

__global__ __launch_bounds__(256) void k_scanA(const u32* __restrict__ hist,
                                               u32* __restrict__ offs,
                                               u32* __restrict__ bsum) {
  __shared__ u32 sh[256];
  int t = threadIdx.x, b = blockIdx.x, i = b * 256 + t;
  u32 v = hist[i];
  u32 run = v;
  sh[t] = run;
  __syncthreads();
  for (int d = 1; d < 256; d <<= 1) {
    u32 y = (t >= d) ? sh[t - d] : 0u;
    __syncthreads();
    run += y;
    sh[t] = run;
    __syncthreads();
  }
  offs[i] = run - v;
  if (t == 255) bsum[b] = run;
}

__global__ __launch_bounds__(512) void k_scanB(u32* __restrict__ bsum) {
  __shared__ u32 sh[512];
  int t = threadIdx.x;
  u32 v = bsum[t];
  u32 run = v;
  sh[t] = run;
  __syncthreads();
  for (int d = 1; d < 512; d <<= 1) {
    u32 y = (t >= d) ? sh[t - d] : 0u;
    __syncthreads();
    run += y;
    sh[t] = run;
    __syncthreads();
  }
  bsum[t] = run - v;
}

__global__ __launch_bounds__(256) void k_scanC(u32* __restrict__ offs,
                                               const u32* __restrict__ bsum, u32 cnt) {
  int t = threadIdx.x, b = blockIdx.x, i = b * 256 + t;
  offs[i] += bsum[b];
  if (i == 0) offs[NPTS] = cnt;
}

// rank[e] = final position of entry e's contribution (sequential write, low-contention atomics)
__global__ __launch_bounds__(256) void k_rank(const int* __restrict__ mo,
                                              const u32* __restrict__ offs,
                                              u32* __restrict__ cur,
                                              u32* __restrict__ rank) {
  int i = blockIdx.x * 256 + threadIdx.x;
  int o = mo[i];
  rank[i] = offs[o] + atomicAdd(&cur[o], 1u);
}

// ---------------- gather-GEMM, natural (k, m-tile) order, rank-scatter rows ----------------
__global__ __launch_bounds__(256) void k_gemm3(const u16* __restrict__ src,
                                               const u16* __restrict__ Wb,
                                               const int* __restrict__ mi,   // group base
                                               const u32* __restrict__ rank, // group-local
                                               u16* __restrict__ contrib,
                                               int kbase) {
  __shared__ u16 As[64 * LDAB];
  __shared__ u16 Bs[128 * LDAB];
  __shared__ u32 sin[64];
  __shared__ u32 srow[64];
  const int t = threadIdx.x;
  const int b = blockIdx.x;
  const int klocal = b >> 10;
  const int i0 = klocal * MMAP + (b & 1023) * 64;

  if (t < 64) {
    sin[t] = (u32)mi[i0 + t];
    srow[t] = rank[i0 + t];
  }
  const uint4* wsrc = (const uint4*)(Wb + (long)(kbase + klocal) * (CD * CD));
#pragma unroll
  for (int i = 0; i < 8; ++i) {
    int q = i * 256 + t;
    int co = q >> 4, cc = q & 15;
    *(uint4*)&Bs[co * LDAB + cc * 8] = wsrc[q];
  }
  __syncthreads();
#pragma unroll
  for (int i = 0; i < 4; ++i) {
    int q = i * 256 + t;
    int r = q >> 4, cc = q & 15;
    long row = sin[r];
    *(uint4*)&As[r * LDAB + cc * 8] = ((const uint4*)(src + row * CD))[cc];
  }
  __syncthreads();

  const int wave = t >> 6, lane = t & 63;
  const int lr = lane & 15, quad = lane >> 4;
  const int wm = (wave & 1) * 32;
  const int wn = (wave >> 1) * 64;
  f32x4 acc[2][4] = {};
#pragma unroll
  for (int kk = 0; kk < 4; ++kk) {
    bf16x8 a[2], bfr[4];
#pragma unroll
    for (int mt = 0; mt < 2; ++mt)
      a[mt] = *(const bf16x8*)&As[(wm + mt * 16 + lr) * LDAB + (kk * 4 + quad) * 8];
#pragma unroll
    for (int nt = 0; nt < 4; ++nt)
      bfr[nt] = *(const bf16x8*)&Bs[(wn + nt * 16 + lr) * LDAB + (kk * 4 + quad) * 8];
#pragma unroll
    for (int mt = 0; mt < 2; ++mt)
#pragma unroll
      for (int nt = 0; nt < 4; ++nt)
        acc[mt][nt] = __builtin_amdgcn_mfma_f32_16x16x32_bf16(a[mt], bfr[nt], acc[mt][nt], 0, 0, 0);
  }

  // repack C through LDS (C/D layout: col = lane&15, row = quad*4+reg), then coalesced row stores
  __syncthreads();
  u16* Cs = As;  // reuse: 64*132 u16 = 16.9KB <= As 17.4KB
#pragma unroll
  for (int mt = 0; mt < 2; ++mt)
#pragma unroll
    for (int v = 0; v < 4; ++v) {
      int slot = wm + mt * 16 + quad * 4 + v;
#pragma unroll
      for (int nt = 0; nt < 4; ++nt)
        Cs[slot * LDC + wn + nt * 16 + lr] = f2bf(acc[mt][nt][v]);
    }
  __syncthreads();
#pragma unroll
  for (int i = 0; i < 4; ++i) {
    int q = i * 256 + t;
    int r = q >> 4, cc = q & 15;
    size_t rk = srow[r];
    *(uint4*)(contrib + rk * CD + cc * 8) = *(const uint4*)&Cs[r * LDC + cc * 8];
  }
}

// ---------------- sequential segmented reduce + optional acc-RMW + fused BN stats ----------------
__global__ __launch_bounds__(256) void k_segreduce3(const u16* __restrict__ contrib,
                                                    const u32* __restrict__ offs,
                                                    float* __restrict__ acc,
                                                    float* __restrict__ stats,
                                                    int first, int last) {
  const int wave = threadIdx.x >> 6, lane = threadIdx.x & 63;
  const int w = blockIdx.x * 4 + wave;  // 4096 waves
  float sx = 0.f, sx2 = 0.f, sy = 0.f, sy2 = 0.f;
  for (int row = w; row < NPTS; row += 4096) {
    u32 s0 = offs[row], s1 = offs[row + 1];
    float a0 = 0.f, b0 = 0.f, a1 = 0.f, b1 = 0.f;
    u32 e = s0;
    for (; e + 2 <= s1; e += 2) {
      u32 d0 = ((const u32*)(contrib + (size_t)e * CD))[lane];
      u32 d1 = ((const u32*)(contrib + (size_t)(e + 1) * CD))[lane];
      a0 += __uint_as_float(d0 << 16);
      b0 += __uint_as_float(d0 & 0xffff0000u);
      a1 += __uint_as_float(d1 << 16);
      b1 += __uint_as_float(d1 & 0xffff0000u);
    }
    if (e < s1) {
      u32 d0 = ((const u32*)(contrib + (size_t)e * CD))[lane];
      a0 += __uint_as_float(d0 << 16);
      b0 += __uint_as_float(d0 & 0xffff0000u);
    }
    float cx = a0 + a1, cy = b0 + b1;
    float2* ap = (float2*)(acc + (size_t)row * CD) + lane;
    if (!first) {
      float2 p = *ap;
      cx += p.x;
      cy += p.y;
    }
    *ap = make_float2(cx, cy);
    if (last) {
      sx += cx;
      sx2 += cx * cx;
      sy += cy;
      sy2 += cy * cy;
    }
  }
  if (last) {
    __shared__ float sh[1024];
    sh[threadIdx.x] = sx;
    sh[256 + threadIdx.x] = sx2;
    sh[512 + threadIdx.x] = sy;
    sh[768 + threadIdx.x] = sy2;
    __syncthreads();
    if (threadIdx.x < 64) {
      int l = threadIdx.x;
      float vx = sh[l] + sh[l + 64] + sh[l + 128] + sh[l + 192];
      float vx2 = sh[256 + l] + sh[256 + l + 64] + sh[256 + l + 128] + sh[256 + l + 192];
      float vy = sh[512 + l] + sh[512 + l + 64] + sh[512 + l + 128] + sh[512 + l + 192];
      float vy2 = sh[768 + l] + sh[768 + l + 64] + sh[768 + l + 128] + sh[768 + l + 192];
      atomicAdd(&stats[2 * l], vx);
      atomicAdd(&stats[128 + 2 * l], vx2);
      atomicAdd(&stats[2 * l + 1], vy);
      atomicAdd(&stats[128 + 2 * l + 1], vy2);
    }
  }
}

// ---------------- BN finalize / apply ----------------
__global__ void k_finalize(const float* __restrict__ stats, const float* __restrict__ gamma,
                           const float* __restrict__ beta, float* __restrict__ scsh) {
  int c = threadIdx.x;
  float mean = stats[c] * (1.f / NPTS);
  float var = stats[128 + c] * (1.f / NPTS) - mean * mean;
  float sc = rsqrtf(var + 1e-5f) * gamma[c];
  scsh[c] = sc;
  scsh[128 + c] = beta[c] - mean * sc;
}

__device__ __forceinline__ float elu(float v) { return v > 0.f ? v : expf(v) - 1.f; }

__global__ __launch_bounds__(256) void k_apply_mid(const float* __restrict__ acc,
                                                   const float* __restrict__ scsh,
                                                   u16* __restrict__ y) {
  long i = ((long)blockIdx.x * 256 + threadIdx.x) * 4;
  int c = (int)(i & 127);
  float4 a = *(const float4*)(acc + i);
  float r0 = elu(a.x * scsh[c] + scsh[128 + c]);
  float r1 = elu(a.y * scsh[c + 1] + scsh[129 + c]);
  float r2 = elu(a.z * scsh[c + 2] + scsh[130 + c]);
  float r3 = elu(a.w * scsh[c + 3] + scsh[131 + c]);
  uint2 v;
  v.x = f2bf(r0) | ((u32)f2bf(r1) << 16);
  v.y = f2bf(r2) | ((u32)f2bf(r3) << 16);
  *(uint2*)(y + i) = v;
}

__global__ __launch_bounds__(256) void k_apply_final(const float* __restrict__ acc,
                                                     const float* __restrict__ scsh,
                                                     const float* __restrict__ x,
                                                     float* __restrict__ out) {
  long i = ((long)blockIdx.x * 256 + threadIdx.x) * 4;
  int c = (int)(i & 127);
  float4 a = *(const float4*)(acc + i);
  float4 rx = *(const float4*)(x + i);
  float4 o;
  o.x = elu(a.x * scsh[c] + scsh[128 + c] + rx.x);
  o.y = elu(a.y * scsh[c + 1] + scsh[129 + c] + rx.y);
  o.z = elu(a.z * scsh[c + 2] + scsh[130 + c] + rx.z);
  o.w = elu(a.w * scsh[c + 3] + scsh[131 + c] + rx.w);
  *(float4*)(out + i) = o;
}

// ---------------- host ----------------
extern "C" void kernel_launch(void* const* d_in, const int* in_sizes, int n_in,
                              void* d_out, int out_size, void* d_ws, size_t ws_size,
                              hipStream_t stream) {
  const float* x = (const float*)d_in[0];
  const float* W1 = (const float*)d_in[1];
  const float* g1 = (const float*)d_in[2];
  const float* b1 = (const float*)d_in[3];
  const float* W2 = (const float*)d_in[4];
  const float* g2 = (const float*)d_in[5];
  const float* b2 = (const float*)d_in[6];
  const int* m1i = (const int*)d_in[7];
  const int* m1o = (const int*)d_in[8];
  const int* m2i = (const int*)d_in[9];
  const int* m2o = (const int*)d_in[10];
  float* out = (float*)d_out;

  char* base = (char*)d_ws;
  size_t off = 0;
  auto alloc = [&](size_t bytes) -> void* {
    void* r = base + off;
    off = (off + bytes + 255) & ~(size_t)255;
    return r;
  };
  u16* xb = (u16*)alloc((size_t)NPTS * CD * 2);
  u16* yb = (u16*)alloc((size_t)NPTS * CD * 2);
  u16* Wb1 = (u16*)alloc((size_t)KOFF * CD * CD * 2);
  u16* Wb2 = (u16*)alloc((size_t)KOFF * CD * CD * 2);
  float* acc = (float*)alloc((size_t)NPTS * CD * 4);
  // contiguous memset region: hist, cur
  u32* hist = (u32*)alloc((size_t)NPTS * 4);
  u32* cur = (u32*)alloc((size_t)NPTS * 4);
  size_t msSize = (size_t)((char*)base + off - (char*)hist);
  u32* offs = (u32*)alloc(((size_t)NPTS + 1) * 4);
  float* stats = (float*)alloc(256 * 4);
  float* scsh = (float*)alloc(256 * 4);
  u32* bsum = (u32*)alloc(512 * 4);

  // remaining ws -> k-group size (contrib 16.78MB + rank 0.26MB per k)
  size_t per_k = (size_t)MMAP * CD * 2 + (size_t)MMAP * 4 + 512;
  size_t avail = (ws_size > off + 4096) ? (ws_size - off - 4096) : 0;
  int kcnt = (int)(avail / per_k);
  if (kcnt < 1) kcnt = 1;
  if (kcnt > KOFF) kcnt = KOFF;
  u32* rank = (u32*)alloc((size_t)kcnt * MMAP * 4);
  u16* contrib = (u16*)alloc((size_t)kcnt * MMAP * CD * 2);

  k_convert_x<<<(NPTS * CD) / 2048, 256, 0, stream>>>(x, xb);
  k_convert_w<<<(KOFF * 2048 + 255) / 256, 256, 0, stream>>>(W1, Wb1);
  k_convert_w<<<(KOFF * 2048 + 255) / 256, 256, 0, stream>>>(W2, Wb2);

  auto run_conv = [&](const u16* srcm, const u16* Wbm, const int* mi, const int* mo) {
    hipMemsetAsync(stats, 0, 1024, stream);
    for (int g0 = 0; g0 < KOFF; g0 += kcnt) {
      int kc = (KOFF - g0 < kcnt) ? (KOFF - g0) : kcnt;
      u32 cnt = (u32)kc * MMAP;
      hipMemsetAsync(hist, 0, msSize, stream);
      k_hist<<<cnt / 256, 256, 0, stream>>>(mo + (long)g0 * MMAP, hist);
      k_scanA<<<512, 256, 0, stream>>>(hist, offs, bsum);
      k_scanB<<<1, 512, 0, stream>>>(bsum);
      k_scanC<<<512, 256, 0, stream>>>(offs, bsum, cnt);
      k_rank<<<cnt / 256, 256, 0, stream>>>(mo + (long)g0 * MMAP, offs, cur, rank);
      k_gemm3<<<kc * 1024, 256, 0, stream>>>(srcm, Wbm, mi + (long)g0 * MMAP, rank, contrib, g0);
      k_segreduce3<<<1024, 256, 0, stream>>>(contrib, offs, acc, stats,
                                             g0 == 0 ? 1 : 0, (g0 + kc == KOFF) ? 1 : 0);
    }
  };

  run_conv(xb, Wb1, m1i, m1o);
  k_finalize<<<1, 128, 0, stream>>>(stats, g1, b1, scsh);
  k_apply_mid<<<(NPTS * CD) / 1024, 256, 0, stream>>>(acc, scsh, yb);

  run_conv(yb, Wb2, m2i, m2o);
  k_finalize<<<1, 128, 0, stream>>>(stats, g2, b2, scsh);
  k_apply_final<<<(NPTS * CD) / 1024, 256, 0, stream>>>(acc, scsh, x, out);
}